// Round 10
// baseline (386.180 us; speedup 1.0000x reference)
//
#include <hip/hip_runtime.h>
#include <math.h>

typedef __bf16 bf16;
typedef bf16 bf16x8 __attribute__((ext_vector_type(8)));
typedef bf16 bf16x4 __attribute__((ext_vector_type(4)));
typedef float f32x4 __attribute__((ext_vector_type(4)));

#define MFMA(a, b, c) __builtin_amdgcn_mfma_f32_16x16x32_bf16((a), (b), (c), 0, 0, 0)

#define GLOAD_LDS16(gp, lp)                                                        \
  __builtin_amdgcn_global_load_lds((const __attribute__((address_space(1))) void*)(gp), \
                                   (__attribute__((address_space(3))) void*)(lp), 16, 0, 0)

// ---------------- workspace layout ----------------
// bf16 element offsets
static const size_t E_WT_ATTN = 0;          // [3072][1024]
static const size_t E_WT_PROJ = 3145728;    // [1024][1024]
static const size_t E_WT_MLP1 = 4194304;    // [4096][1024]
static const size_t E_WT_MLP2 = 8388608;    // [1024][4096]
static const size_t E_LN1     = 12582912;   // [4096][1024]
static const size_t E_QKV     = 16777216;   // [4096][3072]
static const size_t E_VT      = 37748736;   // [B,H,64,T]
static const size_t E_Y       = 41943040;   // [4096][1024]
static const size_t E_LN2     = 46137344;   // [4096][1024]
static const size_t E_H       = 50331648;   // [4096][4096]
// byte offsets
static const size_t BYTE_X2    = 134217728; // float [4096][1024]
static const size_t BYTE_OPART = 150994944; // bf16 [4096][64][64] attn partials
static const size_t BYTE_ML    = 184549376; // float [4096][64][2]
static const size_t BYTE_GPART = 186646528; // float [4][4096][1024] gemm split-K partials
static const size_t TOTAL_BYTES = 253755392;

__device__ __align__(4096) unsigned char g_buf[TOTAL_BYTES];

// ---------------- merged transpose+cast for all 4 weights ----------------
// f32 [K][N] -> bf16 [N][K]
__global__ __launch_bounds__(256) void transpose_all(const float* __restrict__ aw,
                                                     const float* __restrict__ pw,
                                                     const float* __restrict__ m1,
                                                     const float* __restrict__ m2,
                                                     bf16* __restrict__ o_a,
                                                     bf16* __restrict__ o_p,
                                                     bf16* __restrict__ o_m1,
                                                     bf16* __restrict__ o_m2) {
  __shared__ float tile[32][33];
  int bid = blockIdx.x;
  const float* in;
  bf16* out;
  int K, N, tix;
  if (bid < 3072) { in = aw; out = o_a; K = 1024; N = 3072; tix = bid; }
  else if (bid < 4096) { in = pw; out = o_p; K = 1024; N = 1024; tix = bid - 3072; }
  else if (bid < 8192) { in = m1; out = o_m1; K = 1024; N = 4096; tix = bid - 4096; }
  else { in = m2; out = o_m2; K = 4096; N = 1024; tix = bid - 8192; }
  int ntx = N >> 5;
  int bx = tix % ntx, by = tix / ntx;
  int tx = threadIdx.x, ty = threadIdx.y;
#pragma unroll
  for (int i = ty; i < 32; i += 8)
    tile[i][tx] = in[(size_t)(by * 32 + i) * N + bx * 32 + tx];
  __syncthreads();
#pragma unroll
  for (int i = ty; i < 32; i += 8)
    out[(size_t)(bx * 32 + i) * K + by * 32 + tx] = (bf16)tile[tx][i];
}

// ---------------- LayerNorm f32 row(1024) -> bf16 ----------------
__global__ __launch_bounds__(256) void ln_bf16(const float* __restrict__ x,
                                               const float* __restrict__ g,
                                               const float* __restrict__ b,
                                               bf16* __restrict__ out) {
  int row = blockIdx.x, tid = threadIdx.x;
  const float* xr = x + ((size_t)row << 10);
  float4 v = *(const float4*)(xr + tid * 4);
  float s = v.x + v.y + v.z + v.w;
  float ss = v.x * v.x + v.y * v.y + v.z * v.z + v.w * v.w;
#pragma unroll
  for (int off = 32; off >= 1; off >>= 1) {
    s += __shfl_down(s, off);
    ss += __shfl_down(ss, off);
  }
  __shared__ float sh[8];
  int wid = tid >> 6;
  if ((tid & 63) == 0) { sh[wid] = s; sh[wid + 4] = ss; }
  __syncthreads();
  float ts = sh[0] + sh[1] + sh[2] + sh[3];
  float tss = sh[4] + sh[5] + sh[6] + sh[7];
  float mean = ts * (1.0f / 1024.0f);
  float var = tss * (1.0f / 1024.0f) - mean * mean;
  float inv = rsqrtf(var + 1e-5f);
  float4 gg = *(const float4*)(g + tid * 4);
  float4 bb = *(const float4*)(b + tid * 4);
  bf16x4 o;
  o[0] = (bf16)((v.x - mean) * inv * gg.x + bb.x);
  o[1] = (bf16)((v.y - mean) * inv * gg.y + bb.y);
  o[2] = (bf16)((v.z - mean) * inv * gg.z + bb.z);
  o[3] = (bf16)((v.w - mean) * inv * gg.w + bb.w);
  *(bf16x4*)(out + ((size_t)row << 10) + tid * 4) = o;
}

// ---------------- 256x256 GEMM, BK=64, 8 waves, dbuf LDS, swizzled ----------------
// T4 counted-vmcnt pipeline + T5 setprio. C[M][N] = A[M][K] @ Bt[N][K]^T.
// EPI 0: bf16(acc+bias); 1: bf16(gelu(acc+bias)); 3: outf[z*M*N+idx] = acc
template <int EPI>
__global__ __launch_bounds__(512, 2) void gemm256(const bf16* __restrict__ A,
                                                  const bf16* __restrict__ Bt,
                                                  const float* __restrict__ bias,
                                                  bf16* __restrict__ outb,
                                                  float* __restrict__ outf,
                                                  int M, int N, int K, int Kseg) {
  __shared__ __align__(16) bf16 As[2][16384];  // [buf][256*64]
  __shared__ __align__(16) bf16 Bs[2][16384];
  int tid = threadIdx.x;
  // XCD-contiguous tile remap (nwg % 8 == 0 for all our grids)
  int nwg = gridDim.x * gridDim.y;
  int bid = blockIdx.y * gridDim.x + blockIdx.x;
  int id2 = ((nwg & 7) == 0) ? ((bid & 7) * (nwg >> 3) + (bid >> 3)) : bid;
  int bx = id2 % gridDim.x, by = id2 / gridDim.x;
  int lane = tid & 63, wid = tid >> 6;
  int wr = wid >> 2, wc = wid & 3;  // 2 x 4 waves
  int g = lane >> 4, lr = lane & 15;
  f32x4 acc[8][4];
#pragma unroll
  for (int m = 0; m < 8; ++m)
#pragma unroll
    for (int n = 0; n < 4; ++n) acc[m][n] = (f32x4){0.f, 0.f, 0.f, 0.f};
  const bf16* Ab = A + (size_t)by * 256 * K;
  const bf16* Bb = Bt + (size_t)bx * 256 * K;
  int rbase = tid >> 3;
  int srccol = (((tid & 7) ^ (rbase & 7)) << 3);
  const bf16* Asrc = Ab + (size_t)rbase * K + srccol;
  const bf16* Bsrc = Bb + (size_t)rbase * K + srccol;
#define G256_STAGE(buf, k0)                                                \
  {                                                                        \
    _Pragma("unroll") for (int q = 0; q < 4; ++q) {                        \
      GLOAD_LDS16(Asrc + (size_t)(q * 64) * K + (k0), &As[buf][tid * 8 + q * 4096]); \
      GLOAD_LDS16(Bsrc + (size_t)(q * 64) * K + (k0), &Bs[buf][tid * 8 + q * 4096]); \
    }                                                                      \
  }
  int kbeg = blockIdx.z * Kseg;
  int NT = Kseg >> 6;
  // prologue: stage tiles 0 and 1; wait only for tile 0 (tile 1's 8 loads stay in flight)
  G256_STAGE(0, kbeg);
  if (NT > 1) {
    G256_STAGE(1, kbeg + 64);
    asm volatile("s_waitcnt vmcnt(8)" ::: "memory");
  } else {
    asm volatile("s_waitcnt vmcnt(0)" ::: "memory");
  }
  __builtin_amdgcn_sched_barrier(0);
  __builtin_amdgcn_s_barrier();
  int c = 0;
  for (int t = 0; t < NT; ++t) {
    bf16x8 a0[8], b0[4], a1[8], b1[4];
#pragma unroll
    for (int m = 0; m < 8; ++m) {
      int row = wr * 128 + m * 16 + lr;
      a0[m] = *(const bf16x8*)&As[c][row * 64 + ((g ^ (row & 7)) << 3)];
      a1[m] = *(const bf16x8*)&As[c][row * 64 + (((4 + g) ^ (row & 7)) << 3)];
    }
#pragma unroll
    for (int n = 0; n < 4; ++n) {
      int row = wc * 64 + n * 16 + lr;
      b0[n] = *(const bf16x8*)&Bs[c][row * 64 + ((g ^ (row & 7)) << 3)];
      b1[n] = *(const bf16x8*)&Bs[c][row * 64 + (((4 + g) ^ (row & 7)) << 3)];
    }
    // kk=0 MFMA cluster
    __builtin_amdgcn_s_setprio(1);
#pragma unroll
    for (int m = 0; m < 8; ++m)
#pragma unroll
      for (int n = 0; n < 4; ++n) acc[m][n] = MFMA(a0[m], b0[n], acc[m][n]);
    __builtin_amdgcn_s_setprio(0);
    // all ds_reads of buf c complete before anyone overwrites it
    asm volatile("s_waitcnt lgkmcnt(0)" ::: "memory");
    __builtin_amdgcn_sched_barrier(0);
    __builtin_amdgcn_s_barrier();
    if (t + 2 < NT) G256_STAGE(c, kbeg + (t + 2) * 64);  // overwrite c with tile t+2
    // kk=1 MFMA cluster (register operands; overlaps the staging loads)
    __builtin_amdgcn_s_setprio(1);
#pragma unroll
    for (int m = 0; m < 8; ++m)
#pragma unroll
      for (int n = 0; n < 4; ++n) acc[m][n] = MFMA(a1[m], b1[n], acc[m][n]);
    __builtin_amdgcn_s_setprio(0);
    // counted wait: retire tile t+1's 8 loads, keep tile t+2's 8 in flight
    if (t + 2 < NT) {
      asm volatile("s_waitcnt vmcnt(8)" ::: "memory");
    } else if (t + 1 < NT) {
      asm volatile("s_waitcnt vmcnt(0)" ::: "memory");
    }
    __builtin_amdgcn_sched_barrier(0);
    __builtin_amdgcn_s_barrier();  // tile t+1 fully resident in buf c^1
    c ^= 1;
  }
#undef G256_STAGE
  if (EPI == 3) {
    float* po = outf + (size_t)blockIdx.z * M * N;
#pragma unroll
    for (int m = 0; m < 8; ++m) {
#pragma unroll
      for (int n = 0; n < 4; ++n) {
        int rg0 = by * 256 + wr * 128 + m * 16 + g * 4;
        int cg = bx * 256 + wc * 64 + n * 16 + lr;
#pragma unroll
        for (int j = 0; j < 4; ++j) po[(size_t)(rg0 + j) * N + cg] = acc[m][n][j];
      }
    }
  } else {
#pragma unroll
    for (int m = 0; m < 8; ++m) {
#pragma unroll
      for (int n = 0; n < 4; ++n) {
        int rg0 = by * 256 + wr * 128 + m * 16 + g * 4;
        int cg = bx * 256 + wc * 64 + n * 16 + lr;
        float bv = bias[cg];
#pragma unroll
        for (int j = 0; j < 4; ++j) {
          float v = acc[m][n][j] + bv;
          size_t idx = (size_t)(rg0 + j) * N + cg;
          if (EPI == 0)
            outb[idx] = (bf16)v;
          else {
            // exact-gelu via tanh form (branch-free, |err|<0.003)
            float u = 0.7978845608f * (v + 0.044715f * v * v * v);
            float e = exp2f(u * 2.885390082f);  // exp(2u)
            float th = 1.0f - 2.0f / (e + 1.0f);
            outb[idx] = (bf16)(0.5f * v * (1.0f + th));
          }
        }
      }
    }
  }
}

// ---------------- 128x128 GEMM (split-K partial only) ----------------
__global__ __launch_bounds__(256) void gemm_bt3(const bf16* __restrict__ A,
                                                const bf16* __restrict__ Bt,
                                                float* __restrict__ outf,
                                                int M, int N, int K, int Kseg) {
  __shared__ __align__(16) bf16 As[128 * 32];
  __shared__ __align__(16) bf16 Bs[128 * 32];
  int bx = blockIdx.x, by = blockIdx.y;
  int tid = threadIdx.x;
  int lane = tid & 63, wid = tid >> 6;
  int wr = wid >> 1, wc = wid & 1;
  int g = lane >> 4, lr = lane & 15;
  f32x4 acc[4][4];
#pragma unroll
  for (int m = 0; m < 4; ++m)
#pragma unroll
    for (int n = 0; n < 4; ++n) acc[m][n] = (f32x4){0.f, 0.f, 0.f, 0.f};
  const bf16* Ab = A + (size_t)by * 128 * K;
  const bf16* Bb = Bt + (size_t)bx * 128 * K;
  int srow = tid >> 2;
  int sk8 = (tid & 3) * 8;
  const bf16* Ap0 = Ab + (size_t)srow * K + sk8;
  const bf16* Ap1 = Ab + (size_t)(srow + 64) * K + sk8;
  const bf16* Bp0 = Bb + (size_t)srow * K + sk8;
  const bf16* Bp1 = Bb + (size_t)(srow + 64) * K + sk8;
  bf16* lA0 = As + tid * 8;
  bf16* lA1 = As + 2048 + tid * 8;
  bf16* lB0 = Bs + tid * 8;
  bf16* lB1 = Bs + 2048 + tid * 8;
  int kbeg = blockIdx.z * Kseg;
  int kend = kbeg + Kseg;
  for (int k0 = kbeg; k0 < kend; k0 += 32) {
    GLOAD_LDS16(Ap0 + k0, lA0);
    GLOAD_LDS16(Ap1 + k0, lA1);
    GLOAD_LDS16(Bp0 + k0, lB0);
    GLOAD_LDS16(Bp1 + k0, lB1);
    __syncthreads();
    bf16x8 af[4], bfv[4];
#pragma unroll
    for (int m = 0; m < 4; ++m) af[m] = *(const bf16x8*)(As + (wr * 64 + m * 16 + lr) * 32 + g * 8);
#pragma unroll
    for (int n = 0; n < 4; ++n) bfv[n] = *(const bf16x8*)(Bs + (wc * 64 + n * 16 + lr) * 32 + g * 8);
#pragma unroll
    for (int m = 0; m < 4; ++m)
#pragma unroll
      for (int n = 0; n < 4; ++n) acc[m][n] = MFMA(af[m], bfv[n], acc[m][n]);
    __syncthreads();
  }
  float* po = outf + (size_t)blockIdx.z * M * N;
#pragma unroll
  for (int m = 0; m < 4; ++m) {
#pragma unroll
    for (int n = 0; n < 4; ++n) {
      int rg0 = by * 128 + wr * 64 + m * 16 + g * 4;
      int cg = bx * 128 + wc * 64 + n * 16 + lr;
#pragma unroll
      for (int j = 0; j < 4; ++j) po[(size_t)(rg0 + j) * N + cg] = acc[m][n][j];
    }
  }
}

// ---------------- split-K reduce: out = res*w + sum(parts) + bias ----------------
template <int SK>
__global__ __launch_bounds__(256) void reduce_add(const float* __restrict__ part,
                                                  const float* __restrict__ bias,
                                                  const float* __restrict__ res,
                                                  const float* __restrict__ wsc,
                                                  float* __restrict__ out, int MN, int N) {
  size_t i = ((size_t)blockIdx.x * 256 + threadIdx.x) * 4;
  float4 a = *(const float4*)(part + i);
#pragma unroll
  for (int s = 1; s < SK; ++s) {
    float4 b = *(const float4*)(part + (size_t)s * MN + i);
    a.x += b.x; a.y += b.y; a.z += b.z; a.w += b.w;
  }
  int col = (int)(i & (size_t)(N - 1));
  float4 bv = *(const float4*)(bias + col);
  float4 rv = *(const float4*)(res + i);
  float w = wsc[0];
  float4 o;
  o.x = rv.x * w + a.x + bv.x;
  o.y = rv.y * w + a.y + bv.y;
  o.z = rv.z * w + a.z + bv.z;
  o.w = rv.w * w + a.w + bv.w;
  *(float4*)(out + i) = o;
}

// ---------------- fused proj split-K reduce + residual + LayerNorm2 ----------------
__global__ __launch_bounds__(256) void reduce_ln(const float* __restrict__ part,
                                                 const float* __restrict__ bias,
                                                 const float* __restrict__ res,
                                                 const float* __restrict__ wsc,
                                                 const float* __restrict__ lng,
                                                 const float* __restrict__ lnb,
                                                 float* __restrict__ x2out,
                                                 bf16* __restrict__ lnout) {
  int row = blockIdx.x, tid = threadIdx.x;
  size_t i = ((size_t)row << 10) + tid * 4;
  float4 a = *(const float4*)(part + i);
  float4 b2 = *(const float4*)(part + 4194304 + i);
  float4 rv = *(const float4*)(res + i);
  float4 bv = *(const float4*)(bias + tid * 4);
  float w = wsc[0];
  float4 o;
  o.x = rv.x * w + a.x + b2.x + bv.x;
  o.y = rv.y * w + a.y + b2.y + bv.y;
  o.z = rv.z * w + a.z + b2.z + bv.z;
  o.w = rv.w * w + a.w + b2.w + bv.w;
  *(float4*)(x2out + i) = o;
  float s = o.x + o.y + o.z + o.w;
  float ss = o.x * o.x + o.y * o.y + o.z * o.z + o.w * o.w;
#pragma unroll
  for (int off = 32; off >= 1; off >>= 1) {
    s += __shfl_down(s, off);
    ss += __shfl_down(ss, off);
  }
  __shared__ float sh[8];
  int wid = tid >> 6;
  if ((tid & 63) == 0) { sh[wid] = s; sh[wid + 4] = ss; }
  __syncthreads();
  float ts = sh[0] + sh[1] + sh[2] + sh[3];
  float tss = sh[4] + sh[5] + sh[6] + sh[7];
  float mean = ts * (1.0f / 1024.0f);
  float var = tss * (1.0f / 1024.0f) - mean * mean;
  float inv = rsqrtf(var + 1e-5f);
  float4 gg = *(const float4*)(lng + tid * 4);
  float4 bb = *(const float4*)(lnb + tid * 4);
  bf16x4 ov;
  ov[0] = (bf16)((o.x - mean) * inv * gg.x + bb.x);
  ov[1] = (bf16)((o.y - mean) * inv * gg.y + bb.y);
  ov[2] = (bf16)((o.z - mean) * inv * gg.z + bb.z);
  ov[3] = (bf16)((o.w - mean) * inv * gg.w + bb.w);
  *(bf16x4*)(lnout + ((size_t)row << 10) + tid * 4) = ov;
}

// ---------------- V transpose from qkv: vT[bh][d][t] ----------------
__global__ __launch_bounds__(256) void split_v_t(const bf16* __restrict__ qkv,
                                                 bf16* __restrict__ vT) {
  int t0 = blockIdx.x * 32;
  int bh = blockIdx.y;
  int b = bh >> 4, h = bh & 15;
  __shared__ bf16 tile[32][72];
  int tid = threadIdx.x;
  int d = tid & 63, tl0 = tid >> 6;
#pragma unroll
  for (int p = 0; p < 8; ++p) {
    int tl = p * 4 + tl0;
    tile[tl][d] = qkv[((size_t)(b * 2048 + t0 + tl)) * 3072 + 2048 + h * 64 + d];
  }
  __syncthreads();
  int tl = tid & 31, dq = tid >> 5;
#pragma unroll
  for (int p = 0; p < 8; ++p) {
    int dd = p * 8 + dq;
    vT[((size_t)(bh * 64 + dd)) * 2048 + t0 + tl] = tile[tl][dd];
  }
}

// ---------------- flash attention fwd: paired K-tiles, counted vmcnt, split-K=4 ----------------
__global__ __launch_bounds__(256) void attn_fwd(const bf16* __restrict__ qkv,
                                                const bf16* __restrict__ vT,
                                                bf16* __restrict__ o_part,
                                                float* __restrict__ ml_part) {
  __shared__ __align__(16) bf16 Ks[2][4096];
  __shared__ __align__(16) bf16 Vs[2][4096];
  __shared__ bf16 P[4][16][136];
  int id = blockIdx.x;            // 0..4095
  int bh = id & 31;
  int seg = (id >> 5) & 3;
  int qi = ((id >> 7) + bh) & 31; // stagger causal depth
  int tid = threadIdx.x, wid = tid >> 6, lane = tid & 63;
  int g = lane >> 4, lr = lane & 15;
  int b = bh >> 4, h = bh & 15;
  int nk = qi + 1;
  int kt0 = (nk * seg) >> 2;
  int kt1 = (nk * (seg + 1)) >> 2;
  int nt = kt1 - kt0;
  int qrow = qi * 64 + wid * 16 + lr;
  const bf16* Qr = qkv + ((size_t)(b * 2048 + qrow)) * 3072 + h * 64;
  const float beta = 0.18033688f;  // 0.125 * log2(e): fold into Q
  bf16x8 qf[2];
  qf[0] = *(const bf16x8*)(Qr + g * 8);
  qf[1] = *(const bf16x8*)(Qr + 32 + g * 8);
#pragma unroll
  for (int kk = 0; kk < 2; ++kk)
#pragma unroll
    for (int e = 0; e < 8; ++e) qf[kk][e] = (bf16)((float)qf[kk][e] * beta);
  int r0 = tid >> 3, cs0 = ((tid & 7) ^ (r0 & 7)) << 3;
  int c1i = tid + 256;
  int r1 = c1i >> 3, cs1 = ((c1i & 7) ^ (r1 & 7)) << 3;
  const bf16* sK0 = qkv + ((size_t)(b * 2048 + r0)) * 3072 + 1024 + h * 64 + cs0;
  const bf16* sK1 = qkv + ((size_t)(b * 2048 + r1)) * 3072 + 1024 + h * 64 + cs1;
  const bf16* sV0 = vT + (size_t)bh * 131072 + (size_t)r0 * 2048 + cs0;
  const bf16* sV1 = vT + (size_t)bh * 131072 + (size_t)r1 * 2048 + cs1;
  bf16* dK0 = &Ks[0][0] + tid * 8;
  bf16* dK1 = &Ks[0][0] + 2048 + tid * 8;
  bf16* dV0 = &Vs[0][0] + tid * 8;
  bf16* dV1 = &Vs[0][0] + 2048 + tid * 8;
  // over-staged tiles (ktv >= kt1) read in-bounds garbage inside g_buf; never consumed.
#define STAGE_K(bufsel, ktv)                              \
  {                                                       \
    size_t kadv = (size_t)(ktv) * (64 * 3072);            \
    int bo = (bufsel) * 4096;                             \
    GLOAD_LDS16(sK0 + kadv, dK0 + bo);                    \
    GLOAD_LDS16(sK1 + kadv, dK1 + bo);                    \
  }
#define STAGE_V(bufsel, ktv)                              \
  {                                                       \
    size_t vadv = (size_t)(ktv) * 64;                     \
    int bo = (bufsel) * 4096;                             \
    GLOAD_LDS16(sV0 + vadv, dV0 + bo);                    \
    GLOAD_LDS16(sV1 + vadv, dV1 + bo);                    \
  }
  f32x4 o[4];
#pragma unroll
  for (int n = 0; n < 4; ++n) o[n] = (f32x4){0.f, 0.f, 0.f, 0.f};
  float m = -3e38f, l = 0.f;
  int sw = lr & 7;
  int sb = (lane & 48) | (g << 2);
  if (nt > 0) {
    STAGE_K(0, kt0);
    STAGE_K(1, kt0 + 1);
    STAGE_V(0, kt0);
    STAGE_V(1, kt0 + 1);
  }
  int kt = kt0;
  // -------- pair loop: tiles (kt, kt+1), one combined softmax over 128 cols --------
  for (; kt + 2 <= kt1; kt += 2) {
    asm volatile("s_waitcnt vmcnt(4)" ::: "memory");  // K pair resident
    __builtin_amdgcn_sched_barrier(0);
    __builtin_amdgcn_s_barrier();
    f32x4 s0[4], s1[4];
#pragma unroll
    for (int n = 0; n < 4; ++n) { s0[n] = (f32x4){0.f,0.f,0.f,0.f}; s1[n] = (f32x4){0.f,0.f,0.f,0.f}; }
    __builtin_amdgcn_s_setprio(1);
#pragma unroll
    for (int kk = 0; kk < 2; ++kk) {
#pragma unroll
      for (int n = 0; n < 4; ++n) {
        int off = ((n * 16 + lr) << 6) + ((((kk << 2) + g) ^ sw) << 3);
        bf16x8 kf0 = *(const bf16x8*)(&Ks[0][0] + off);
        s0[n] = MFMA(kf0, qf[kk], s0[n]);
        bf16x8 kf1 = *(const bf16x8*)(&Ks[1][0] + off);
        s1[n] = MFMA(kf1, qf[kk], s1[n]);
      }
    }
    __builtin_amdgcn_s_setprio(0);
    asm volatile("s_waitcnt lgkmcnt(0)" ::: "memory");  // all K reads done
    __builtin_amdgcn_sched_barrier(0);
    __builtin_amdgcn_s_barrier();
    STAGE_K(0, kt + 2);
    STAGE_K(1, kt + 3);
    if (kt + 1 == qi) {  // diagonal can only be the second tile of the pair
      int kc0 = (kt + 1) * 64 + g * 4;
#pragma unroll
      for (int n = 0; n < 4; ++n)
#pragma unroll
        for (int j = 0; j < 4; ++j)
          if ((kc0 + n * 16 + j) > qrow) s1[n][j] = -3e38f;
    }
    // combined online softmax over both tiles (32 values/lane)
    float mx = s0[0][0];
#pragma unroll
    for (int n = 0; n < 4; ++n)
#pragma unroll
      for (int j = 0; j < 4; ++j) { mx = fmaxf(mx, s0[n][j]); mx = fmaxf(mx, s1[n][j]); }
    mx = fmaxf(mx, __shfl_xor(mx, 16));
    mx = fmaxf(mx, __shfl_xor(mx, 32));
    bool defer = __all(mx <= m + 11.5416f);
    float mn = m, al = 0.f;
    if (!defer) {
      mn = fmaxf(m, mx);
      al = exp2f(m - mn);
      m = mn;
    }
    float rs = 0.f;
    bf16x4 pw0[4], pw1[4];
#pragma unroll
    for (int n = 0; n < 4; ++n)
#pragma unroll
      for (int j = 0; j < 4; ++j) {
        float p0 = exp2f(s0[n][j] - mn);
        float p1 = exp2f(s1[n][j] - mn);
        rs += p0 + p1;
        pw0[n][j] = (bf16)p0;
        pw1[n][j] = (bf16)p1;
      }
    rs += __shfl_xor(rs, 16);
    rs += __shfl_xor(rs, 32);
    if (defer) {
      l += rs;
    } else {
      l = l * al + rs;
      float alj[4];
#pragma unroll
      for (int j = 0; j < 4; ++j) alj[j] = __shfl(al, sb + j);
#pragma unroll
      for (int n = 0; n < 4; ++n)
#pragma unroll
        for (int j = 0; j < 4; ++j) o[n][j] *= alj[j];
    }
#pragma unroll
    for (int n = 0; n < 4; ++n) {
      *(bf16x4*)&P[wid][lr][n * 16 + g * 4] = pw0[n];
      *(bf16x4*)&P[wid][lr][64 + n * 16 + g * 4] = pw1[n];
    }
    asm volatile("s_waitcnt vmcnt(4)" ::: "memory");  // V pair resident
    __builtin_amdgcn_sched_barrier(0);
    __builtin_amdgcn_s_barrier();
    __builtin_amdgcn_s_setprio(1);
#pragma unroll
    for (int kk = 0; kk < 2; ++kk) {
      bf16x8 pf0 = *(const bf16x8*)&P[wid][lr][kk * 32 + g * 8];
      bf16x8 pf1 = *(const bf16x8*)&P[wid][lr][64 + kk * 32 + g * 8];
#pragma unroll
      for (int n = 0; n < 4; ++n) {
        int off = ((n * 16 + lr) << 6) + ((((kk << 2) + g) ^ sw) << 3);
        bf16x8 vf0 = *(const bf16x8*)(&Vs[0][0] + off);
        o[n] = MFMA(pf0, vf0, o[n]);
        bf16x8 vf1 = *(const bf16x8*)(&Vs[1][0] + off);
        o[n] = MFMA(pf1, vf1, o[n]);
      }
    }
    __builtin_amdgcn_s_setprio(0);
    asm volatile("s_waitcnt lgkmcnt(0)" ::: "memory");  // all V reads done
    __builtin_amdgcn_sched_barrier(0);
    __builtin_amdgcn_s_barrier();
    STAGE_V(0, kt + 2);
    STAGE_V(1, kt + 3);
  }
  // -------- tail: single tile --------
  if (kt < kt1) {
    int lb = (kt - kt0) & 1;
    asm volatile("s_waitcnt vmcnt(4)" ::: "memory");  // K(tail) resident
    __builtin_amdgcn_sched_barrier(0);
    __builtin_amdgcn_s_barrier();
    f32x4 s0[4];
#pragma unroll
    for (int n = 0; n < 4; ++n) s0[n] = (f32x4){0.f,0.f,0.f,0.f};
    __builtin_amdgcn_s_setprio(1);
#pragma unroll
    for (int kk = 0; kk < 2; ++kk) {
#pragma unroll
      for (int n = 0; n < 4; ++n) {
        int off = ((n * 16 + lr) << 6) + ((((kk << 2) + g) ^ sw) << 3);
        bf16x8 kf = *(const bf16x8*)(&Ks[lb][0] + off);
        s0[n] = MFMA(kf, qf[kk], s0[n]);
      }
    }
    __builtin_amdgcn_s_setprio(0);
    if (kt == qi) {
      int kc0 = kt * 64 + g * 4;
#pragma unroll
      for (int n = 0; n < 4; ++n)
#pragma unroll
        for (int j = 0; j < 4; ++j)
          if ((kc0 + n * 16 + j) > qrow) s0[n][j] = -3e38f;
    }
    float mx = s0[0][0];
#pragma unroll
    for (int n = 0; n < 4; ++n)
#pragma unroll
      for (int j = 0; j < 4; ++j) mx = fmaxf(mx, s0[n][j]);
    mx = fmaxf(mx, __shfl_xor(mx, 16));
    mx = fmaxf(mx, __shfl_xor(mx, 32));
    bool defer = __all(mx <= m + 11.5416f);
    float mn = m, al = 0.f;
    if (!defer) {
      mn = fmaxf(m, mx);
      al = exp2f(m - mn);
      m = mn;
    }
    float rs = 0.f;
    bf16x4 pw0[4];
#pragma unroll
    for (int n = 0; n < 4; ++n)
#pragma unroll
      for (int j = 0; j < 4; ++j) {
        float p = exp2f(s0[n][j] - mn);
        rs += p;
        pw0[n][j] = (bf16)p;
      }
    rs += __shfl_xor(rs, 16);
    rs += __shfl_xor(rs, 32);
    if (defer) {
      l += rs;
    } else {
      l = l * al + rs;
      float alj[4];
#pragma unroll
      for (int j = 0; j < 4; ++j) alj[j] = __shfl(al, sb + j);
#pragma unroll
      for (int n = 0; n < 4; ++n)
#pragma unroll
        for (int j = 0; j < 4; ++j) o[n][j] *= alj[j];
    }
#pragma unroll
    for (int n = 0; n < 4; ++n) *(bf16x4*)&P[wid][lr][n * 16 + g * 4] = pw0[n];
    asm volatile("s_waitcnt vmcnt(0)" ::: "memory");  // V(tail) resident
    __builtin_amdgcn_sched_barrier(0);
    __builtin_amdgcn_s_barrier();
    __builtin_amdgcn_s_setprio(1);
#pragma unroll
    for (int kk = 0; kk < 2; ++kk) {
      bf16x8 pf = *(const bf16x8*)&P[wid][lr][kk * 32 + g * 8];
#pragma unroll
      for (int n = 0; n < 4; ++n) {
        int off = ((n * 16 + lr) << 6) + ((((kk << 2) + g) ^ sw) << 3);
        bf16x8 vf = *(const bf16x8*)(&Vs[lb][0] + off);
        o[n] = MFMA(pf, vf, o[n]);
      }
    }
    __builtin_amdgcn_s_setprio(0);
  }
  bf16* ob = o_part + (size_t)id * 4096;
#pragma unroll
  for (int n = 0; n < 4; ++n)
#pragma unroll
    for (int j = 0; j < 4; ++j)
      ob[(size_t)(wid * 16 + g * 4 + j) * 64 + n * 16 + lr] = (bf16)o[n][j];
  if (lane < 16) {
    ml_part[(size_t)id * 128 + (wid * 16 + lane) * 2] = m;
    ml_part[(size_t)id * 128 + (wid * 16 + lane) * 2 + 1] = l;
  }
#undef STAGE_K
#undef STAGE_V
}

// ---------------- attention combine: 4-way merge, bf16 partials ----------------
__global__ __launch_bounds__(256) void attn_combine(const bf16* __restrict__ o_part,
                                                    const float* __restrict__ ml_part,
                                                    bf16* __restrict__ y) {
  int c = blockIdx.x;  // 0..1023: (bh, qi)
  int bh = c & 31, qi = c >> 5;
  int b = bh >> 4, h = bh & 15;
  int qraw = (qi - bh) & 31;
  size_t idbase = (size_t)bh + ((size_t)qraw << 7);
  int t = threadIdx.x;
  int r = t >> 2, cq = (t & 3) << 4;
  float mv[4], lv[4];
#pragma unroll
  for (int s = 0; s < 4; ++s) {
    size_t ids = idbase + ((size_t)s << 5);
    mv[s] = ml_part[ids * 128 + r * 2];
    lv[s] = ml_part[ids * 128 + r * 2 + 1];
  }
  float mm = fmaxf(fmaxf(mv[0], mv[1]), fmaxf(mv[2], mv[3]));
  float ws[4], denom = 0.f;
#pragma unroll
  for (int s = 0; s < 4; ++s) {
    ws[s] = exp2f(mv[s] - mm);
    denom += lv[s] * ws[s];
  }
  float inv = 1.0f / denom;
  float accv[16];
#pragma unroll
  for (int u = 0; u < 16; ++u) accv[u] = 0.f;
#pragma unroll
  for (int s = 0; s < 4; ++s) {
    const bf16* ps = o_part + (idbase + ((size_t)s << 5)) * 4096 + r * 64 + cq;
    bf16x8 v0 = *(const bf16x8*)ps;
    bf16x8 v1 = *(const bf16x8*)(ps + 8);
    float w = ws[s];
#pragma unroll
    for (int u = 0; u < 8; ++u) {
      accv[u] += (float)v0[u] * w;
      accv[8 + u] += (float)v1[u] * w;
    }
  }
  bf16* yp = y + ((size_t)(b * 2048 + qi * 64 + r)) * 1024 + h * 64 + cq;
  bf16x8 ov0, ov1;
#pragma unroll
  for (int u = 0; u < 8; ++u) {
    ov0[u] = (bf16)(accv[u] * inv);
    ov1[u] = (bf16)(accv[8 + u] * inv);
  }
  *(bf16x8*)yp = ov0;
  *(bf16x8*)(yp + 8) = ov1;
}

// ---------------- launch ----------------
extern "C" void kernel_launch(void* const* d_in, const int* in_sizes, int n_in,
                              void* d_out, int out_size, void* d_ws, size_t ws_size,
                              hipStream_t stream) {
  const float* x = (const float*)d_in[0];
  const float* ln1_g = (const float*)d_in[1];
  const float* ln1_b = (const float*)d_in[2];
  const float* attn_w = (const float*)d_in[3];
  const float* attn_b = (const float*)d_in[4];
  const float* proj_w = (const float*)d_in[5];
  const float* proj_b = (const float*)d_in[6];
  const float* ln2_g = (const float*)d_in[7];
  const float* ln2_b = (const float*)d_in[8];
  const float* mlp_w1 = (const float*)d_in[9];
  const float* mlp_b1 = (const float*)d_in[10];
  const float* mlp_w2 = (const float*)d_in[11];
  const float* mlp_b2 = (const float*)d_in[12];
  const float* w_att = (const float*)d_in[13];
  const float* w_mlp = (const float*)d_in[14];
  float* out = (float*)d_out;

  unsigned char* base = nullptr;
  if (ws_size >= TOTAL_BYTES) {
    base = (unsigned char*)d_ws;
  } else {
    hipGetSymbolAddress((void**)&base, HIP_SYMBOL(g_buf));
  }
  bf16* bb = (bf16*)base;
  bf16* wt_attn = bb + E_WT_ATTN;
  bf16* wt_proj = bb + E_WT_PROJ;
  bf16* wt_mlp1 = bb + E_WT_MLP1;
  bf16* wt_mlp2 = bb + E_WT_MLP2;
  bf16* ln1o = bb + E_LN1;
  bf16* qkv = bb + E_QKV;
  bf16* vTb = bb + E_VT;
  bf16* yb = bb + E_Y;
  bf16* ln2o = bb + E_LN2;
  bf16* hb = bb + E_H;
  float* x2 = (float*)(base + BYTE_X2);
  bf16* o_part = (bf16*)(base + BYTE_OPART);
  float* ml_part = (float*)(base + BYTE_ML);
  float* gpart = (float*)(base + BYTE_GPART);

  transpose_all<<<12288, dim3(32, 8), 0, stream>>>(attn_w, proj_w, mlp_w1, mlp_w2,
                                                   wt_attn, wt_proj, wt_mlp1, wt_mlp2);

  ln_bf16<<<4096, 256, 0, stream>>>(x, ln1_g, ln1_b, ln1o);

  gemm256<0><<<dim3(12, 16, 1), 512, 0, stream>>>(ln1o, wt_attn, attn_b, qkv, nullptr,
                                                  4096, 3072, 1024, 1024);

  split_v_t<<<dim3(64, 32), 256, 0, stream>>>(qkv, vTb);

  attn_fwd<<<4096, 256, 0, stream>>>(qkv, vTb, o_part, ml_part);
  attn_combine<<<1024, 256, 0, stream>>>(o_part, ml_part, yb);

  gemm_bt3<<<dim3(8, 32, 2), 256, 0, stream>>>(yb, wt_proj, gpart, 4096, 1024, 1024, 512);
  reduce_ln<<<4096, 256, 0, stream>>>(gpart, proj_b, x, w_att, ln2_g, ln2_b, x2, ln2o);

  gemm256<1><<<dim3(16, 16, 1), 512, 0, stream>>>(ln2o, wt_mlp1, mlp_b1, hb, nullptr,
                                                  4096, 4096, 1024, 1024);

  gemm256<3><<<dim3(4, 16, 4), 512, 0, stream>>>(hb, wt_mlp2, nullptr, nullptr, gpart,
                                                 4096, 1024, 4096, 1024);
  reduce_add<4><<<4096, 256, 0, stream>>>(gpart, mlp_b2, x2, w_mlp, out, 4194304, 1024);
}